// Round 1
// baseline (337.069 us; speedup 1.0000x reference)
//
#include <hip/hip_runtime.h>
#include <hip/hip_bf16.h>

#define EPS 1e-10f

// One-pass memory-bound reduction:
//   elem = (y==0) ? -log(1-p+eps) : -lamda*log(p+eps)
// Rewritten as -coef*log(arg) with per-lane cndmask'd arg/coef -> exactly one
// v_log_f32 per element, no divergent branches.
__global__ __launch_bounds__(256) void sparse_loss_kernel(
    const float* __restrict__ pred,
    const int* __restrict__ y,
    const int* __restrict__ lamda_p,
    float* __restrict__ out,
    long long nvec,          // number of float4 groups
    long long total,         // total element count
    float inv_total) {
  const float lam = (float)(*lamda_p);  // uniform scalar load

  float acc = 0.0f;  // accumulates +coef*log(arg); negate at the end

  const long long tid = (long long)blockIdx.x * blockDim.x + threadIdx.x;
  const long long stride = (long long)gridDim.x * blockDim.x;

  for (long long i = tid; i < nvec; i += stride) {
    const float4 p = reinterpret_cast<const float4*>(pred)[i];
    const int4 yy = reinterpret_cast<const int4*>(y)[i];

    {
      const bool z = (yy.x == 0);
      const float a = z ? (1.0f - p.x + EPS) : (p.x + EPS);
      const float c = z ? 1.0f : lam;
      acc = fmaf(c, __logf(a), acc);
    }
    {
      const bool z = (yy.y == 0);
      const float a = z ? (1.0f - p.y + EPS) : (p.y + EPS);
      const float c = z ? 1.0f : lam;
      acc = fmaf(c, __logf(a), acc);
    }
    {
      const bool z = (yy.z == 0);
      const float a = z ? (1.0f - p.z + EPS) : (p.z + EPS);
      const float c = z ? 1.0f : lam;
      acc = fmaf(c, __logf(a), acc);
    }
    {
      const bool z = (yy.w == 0);
      const float a = z ? (1.0f - p.w + EPS) : (p.w + EPS);
      const float c = z ? 1.0f : lam;
      acc = fmaf(c, __logf(a), acc);
    }
  }

  // scalar tail (total not divisible by 4 — not the case here, but cheap)
  for (long long i = nvec * 4 + tid; i < total; i += stride) {
    const float p = pred[i];
    const bool z = (y[i] == 0);
    const float a = z ? (1.0f - p + EPS) : (p + EPS);
    const float c = z ? 1.0f : lam;
    acc = fmaf(c, __logf(a), acc);
  }

  // wave64 butterfly reduce
  for (int off = 32; off > 0; off >>= 1)
    acc += __shfl_down(acc, off, 64);

  __shared__ float ssum[4];  // 256 threads = 4 waves
  const int lane = threadIdx.x & 63;
  const int wave = threadIdx.x >> 6;
  if (lane == 0) ssum[wave] = acc;
  __syncthreads();

  if (threadIdx.x == 0) {
    float b = ssum[0] + ssum[1] + ssum[2] + ssum[3];
    // loss = -mean; scale per-block so the atomic accumulator stays O(3)
    atomicAdd(out, -b * inv_total);
  }
}

extern "C" void kernel_launch(void* const* d_in, const int* in_sizes, int n_in,
                              void* d_out, int out_size, void* d_ws, size_t ws_size,
                              hipStream_t stream) {
  const float* pred = (const float*)d_in[0];
  const int* y = (const int*)d_in[1];
  const int* lamda = (const int*)d_in[2];
  float* out = (float*)d_out;

  const long long total = (long long)in_sizes[0];
  const long long nvec = total / 4;
  const float inv_total = 1.0f / (float)total;

  // d_out is re-poisoned to 0xAA before every timed launch -> zero it each call
  hipMemsetAsync(out, 0, sizeof(float), stream);

  const int block = 256;
  const int grid = 2048;  // 8 blocks/CU * 4 waves = 32 waves/CU (full occupancy)
  sparse_loss_kernel<<<grid, block, 0, stream>>>(pred, y, lamda, out, nvec,
                                                 total, inv_total);
}

// Round 2
// 330.365 us; speedup vs baseline: 1.0203x; 1.0203x over previous
//
#include <hip/hip_runtime.h>
#include <hip/hip_bf16.h>

#define EPS 1e-10f

// Latency-fix revision: manual 4x unroll so each thread has 8 outstanding
// 16B loads (128 B) before the first dependent use. R1 showed VGPR=16 (no
// compiler unroll) -> 1.3 TB/s latency-bound at 16% HBM.
__global__ __launch_bounds__(256) void sparse_loss_kernel(
    const float* __restrict__ pred,
    const int* __restrict__ y,
    const int* __restrict__ lamda_p,
    float* __restrict__ out,
    long long nvec,          // number of float4 groups
    long long total,         // total element count
    float inv_total) {
  const float lam = (float)(*lamda_p);  // uniform scalar load

  float acc = 0.0f;  // accumulates +coef*log(arg); negate at the end

  const long long tid = (long long)blockIdx.x * blockDim.x + threadIdx.x;
  const long long stride = (long long)gridDim.x * blockDim.x;

  const float4* __restrict__ pv = reinterpret_cast<const float4*>(pred);
  const int4* __restrict__ yv = reinterpret_cast<const int4*>(y);

  long long i = tid;

  // main: 4 float4 + 4 int4 loads issued back-to-back, then 16 elems computed
  for (; i + 3 * stride < nvec; i += 4 * stride) {
    float4 p0 = pv[i];
    float4 p1 = pv[i + stride];
    float4 p2 = pv[i + 2 * stride];
    float4 p3 = pv[i + 3 * stride];
    int4 y0 = yv[i];
    int4 y1 = yv[i + stride];
    int4 y2 = yv[i + 2 * stride];
    int4 y3 = yv[i + 3 * stride];

#define ELEM(P, Y)                                              \
  {                                                             \
    const bool z = ((Y) == 0);                                  \
    const float a = EPS + (z ? (1.0f - (P)) : (P));             \
    const float c = z ? 1.0f : lam;                             \
    acc = fmaf(c, __logf(a), acc);                              \
  }
#define VEC4(P, Y)                                              \
  ELEM(P.x, Y.x) ELEM(P.y, Y.y) ELEM(P.z, Y.z) ELEM(P.w, Y.w)

    VEC4(p0, y0)
    VEC4(p1, y1)
    VEC4(p2, y2)
    VEC4(p3, y3)
  }

  // remainder vec4 groups
  for (; i < nvec; i += stride) {
    float4 p = pv[i];
    int4 yy = yv[i];
    VEC4(p, yy)
  }

  // scalar tail (total % 4 != 0 — not the case here, but cheap)
  for (long long j = nvec * 4 + tid; j < total; j += stride) {
    const float p = pred[j];
    ELEM(p, y[j])
  }
#undef VEC4
#undef ELEM

  // wave64 butterfly reduce
  for (int off = 32; off > 0; off >>= 1)
    acc += __shfl_down(acc, off, 64);

  __shared__ float ssum[4];  // 256 threads = 4 waves
  const int lane = threadIdx.x & 63;
  const int wave = threadIdx.x >> 6;
  if (lane == 0) ssum[wave] = acc;
  __syncthreads();

  if (threadIdx.x == 0) {
    float b = ssum[0] + ssum[1] + ssum[2] + ssum[3];
    // loss = -mean; scale per-block so the atomic accumulator stays O(3)
    atomicAdd(out, -b * inv_total);
  }
}

extern "C" void kernel_launch(void* const* d_in, const int* in_sizes, int n_in,
                              void* d_out, int out_size, void* d_ws, size_t ws_size,
                              hipStream_t stream) {
  const float* pred = (const float*)d_in[0];
  const int* y = (const int*)d_in[1];
  const int* lamda = (const int*)d_in[2];
  float* out = (float*)d_out;

  const long long total = (long long)in_sizes[0];
  const long long nvec = total / 4;
  const float inv_total = 1.0f / (float)total;

  // d_out is re-poisoned to 0xAA before every timed launch -> zero it each call
  hipMemsetAsync(out, 0, sizeof(float), stream);

  const int block = 256;
  const int grid = 2048;  // 8 blocks/CU * 4 waves = 32 waves/CU (full occupancy)
  sparse_loss_kernel<<<grid, block, 0, stream>>>(pred, y, lamda, out, nvec,
                                                 total, inv_total);
}